// Round 15
// baseline (548.685 us; speedup 1.0000x reference)
//
#include <hip/hip_runtime.h>
#include <hip/hip_bf16.h>

#define HID 256
#define NGRAPH 2048

typedef __attribute__((ext_vector_type(8))) short s16x8;
typedef __attribute__((ext_vector_type(4))) float f32x4v;

__device__ inline short f2b(float f) {
    __hip_bfloat16 b = __float2bfloat16(f);
    return *reinterpret_cast<short*>(&b);
}
__device__ inline float b2f(short s) {
    return __uint_as_float(((unsigned)(unsigned short)s) << 16);
}
__device__ inline float b2f_lo(unsigned int v) {
    return __uint_as_float(v << 16);
}
__device__ inline float b2f_hi(unsigned int v) {
    return __uint_as_float(v & 0xffff0000u);
}

// ---------------- Atom encoder: h bf16 ----------------
__global__ __launch_bounds__(256) void atom_enc(const int* __restrict__ x,
                                                const float* __restrict__ emb,
                                                short* __restrict__ hb, int N) {
    int n = blockIdx.x;
    int c = threadIdx.x;
    if (n >= N) return;
    const int offs[9] = {0, 119, 124, 136, 148, 158, 164, 170, 172};
    float s = 0.f;
#pragma unroll
    for (int j = 0; j < 9; ++j) {
        int row = x[n * 9 + j] + offs[j];
        s += emb[row * 256 + c];
    }
    hb[n * 256 + c] = f2b(s);
}

// ---------------- Weight prep ----------------
__global__ void prep_wt(const float* __restrict__ bases_W, const float* __restrict__ comb_W,
                        short* __restrict__ WT) {
    int l = blockIdx.x / 224;
    int n = blockIdx.x % 224;
    int k = threadIdx.x;  // 0..255
    float v = (n < 128) ? bases_W[((size_t)l * 256 + k) * 128 + n]
                        : comb_W[((size_t)l * 256 + k) * 96 + (n - 128)];
    WT[((size_t)l * 224 + n) * 256 + k] = f2b(v);
}

// ---------------- CSR build ----------------
__global__ void csr_count(const int* __restrict__ ei, int E, int* cnt) {
    int e = blockIdx.x * blockDim.x + threadIdx.x;
    if (e >= E) return;
    atomicAdd(&cnt[ei[e]], 1);
}

// hierarchical scan: S1 per-1024-chunk sums (addone: +1/elem for self-loops)
__global__ __launch_bounds__(256) void scan_s1(const int* __restrict__ cnt, int* __restrict__ blksum,
                                               int N, int addone) {
    __shared__ int red[256];
    int base = blockIdx.x * 1024;
    int s = 0;
#pragma unroll
    for (int q = 0; q < 4; ++q) {
        int i = base + threadIdx.x * 4 + q;
        s += (i < N) ? (cnt[i] + addone) : 0;
    }
    red[threadIdx.x] = s;
    __syncthreads();
    for (int off = 128; off > 0; off >>= 1) {
        if (threadIdx.x < off) red[threadIdx.x] += red[threadIdx.x + off];
        __syncthreads();
    }
    if (threadIdx.x == 0) blksum[blockIdx.x] = red[0];
}

// S2: exclusive scan of block sums (nb <= 256), writes total to row_ptr[N]
__global__ __launch_bounds__(256) void scan_s2(int* __restrict__ blksum, int nb, int* __restrict__ row_ptr, int N) {
    __shared__ int buf[256];
    int v = (threadIdx.x < nb) ? blksum[threadIdx.x] : 0;
    buf[threadIdx.x] = v;
    __syncthreads();
    for (int off = 1; off < 256; off <<= 1) {
        int t = (threadIdx.x >= off) ? buf[threadIdx.x - off] : 0;
        __syncthreads();
        buf[threadIdx.x] += t;
        __syncthreads();
    }
    if (threadIdx.x < nb) blksum[threadIdx.x] = buf[threadIdx.x] - v;  // exclusive
    if (threadIdx.x == 0) row_ptr[N] = buf[255];
}

// S3: per-chunk local scan + base; writes two copies (row_ptr, woff)
__global__ __launch_bounds__(256) void scan_s3(const int* __restrict__ cnt, const int* __restrict__ blksum,
                                               int* __restrict__ row_ptr, int* __restrict__ woff,
                                               int N, int addone) {
    __shared__ int buf[256];
    int base = blockIdx.x * 1024;
    int i0 = base + threadIdx.x * 4;
    int v[4];
    int s = 0;
#pragma unroll
    for (int q = 0; q < 4; ++q) {
        int i = i0 + q;
        v[q] = (i < N) ? (cnt[i] + addone) : 0;
        s += v[q];
    }
    buf[threadIdx.x] = s;
    __syncthreads();
    for (int off = 1; off < 256; off <<= 1) {
        int t = (threadIdx.x >= off) ? buf[threadIdx.x - off] : 0;
        __syncthreads();
        buf[threadIdx.x] += t;
        __syncthreads();
    }
    int excl = buf[threadIdx.x] - s + blksum[blockIdx.x];
#pragma unroll
    for (int q = 0; q < 4; ++q) {
        int i = i0 + q;
        if (i < N) { row_ptr[i] = excl; woff[i] = excl; }
        excl += v[q];
    }
}

// ---------------- Bucketed edge sort (dst>>8 buckets) ----------------
__global__ __launch_bounds__(256) void ph_hist(const int* __restrict__ ei, int E, int T,
                                               int PB, int NBK, int* __restrict__ mcnt) {
    __shared__ int hist[256];
    hist[threadIdx.x] = 0;
    __syncthreads();
    int base = blockIdx.x * 4096;
#pragma unroll
    for (int q = 0; q < 16; ++q) {
        int i = base + q * 256 + threadIdx.x;
        if (i < T) {
            int d = (i < E) ? ei[i] : (i - E);
            atomicAdd(&hist[d >> 8], 1);
        }
    }
    __syncthreads();
    if (threadIdx.x < NBK) mcnt[threadIdx.x * PB + blockIdx.x] = hist[threadIdx.x];
}

__global__ __launch_bounds__(256) void ph_scatter(const int* __restrict__ ei, int E, int T,
                                                  int PB, int NBK, const int* __restrict__ moff,
                                                  uint2* __restrict__ pairs) {
    __shared__ int off[256];
    if (threadIdx.x < NBK) off[threadIdx.x] = moff[threadIdx.x * PB + blockIdx.x];
    __syncthreads();
    int base = blockIdx.x * 4096;
#pragma unroll
    for (int q = 0; q < 16; ++q) {
        int i = base + q * 256 + threadIdx.x;
        if (i < T) {
            int d, s;
            if (i < E) { d = ei[i]; s = ei[E + i]; }
            else       { d = i - E; s = i - E; }
            int pos = atomicAdd(&off[d >> 8], 1);
            pairs[pos] = make_uint2((unsigned)d, (unsigned)s);
        }
    }
}

__global__ __launch_bounds__(256) void ph_sort(const uint2* __restrict__ pairs,
                                               const int* __restrict__ row_ptr,
                                               const int* __restrict__ moff,
                                               int NBK, int PB, int T,
                                               int* __restrict__ srcs) {
    __shared__ int wcnt[256];
    wcnt[threadIdx.x] = 0;
    __syncthreads();
    int bin = blockIdx.x;
    int p0 = moff[bin * PB];
    int p1 = (bin + 1 < NBK) ? moff[(bin + 1) * PB] : T;
    for (int i = p0 + threadIdx.x; i < p1; i += 256) {
        uint2 u = pairs[i];
        int d = (int)u.x;
        int rank = atomicAdd(&wcnt[d & 255], 1);
        srcs[row_ptr[d] + rank] = (int)u.y;
    }
}

// ---------------- MFMA GEMM, fused BN-apply+residual, all-bf16 h/outb/wts ----------------
__global__ __launch_bounds__(256) void gemm_mfma(short* hb,
                                                 const short* __restrict__ outb,
                                                 const float* __restrict__ ss,
                                                 int do_bn,
                                                 const short* __restrict__ WT,
                                                 const float* __restrict__ cb,
                                                 short* __restrict__ bases,
                                                 short* __restrict__ wts, int N) {
    __shared__ short bs[2][32 * 256];  // 2 x 16KB
    int tid = threadIdx.x;
    int wid = tid >> 6;
    int lane = tid & 63;
    int m0 = blockIdx.x * 64 + wid * 16;
    int row_orig = m0 + (lane & 15);
    bool owner = (row_orig < N);
    int row_a = owner ? row_orig : (N - 1);
    int kgrp = (lane >> 4) * 8;  // 0,8,16,24

    s16x8 a[8];
    if (do_bn) {
#pragma unroll
        for (int i = 0; i < 8; ++i) {
            int cbase = i * 32 + kgrp;
            size_t base = (size_t)row_a * 256 + cbase;
            s16x8 hv = *(const s16x8*)&hb[base];
            s16x8 ov = *(const s16x8*)&outb[base];
            s16x8 t;
#pragma unroll
            for (int k = 0; k < 8; ++k) {
                float hf = b2f(hv[k]);
                float of = b2f(ov[k]);
                float sc = ss[cbase + k];
                float sh = ss[256 + cbase + k];
                hf += fmaxf(of * sc + sh, 0.f);
                t[k] = f2b(hf);
            }
            if (owner) *(s16x8*)&hb[base] = t;
            a[i] = t;
        }
    } else {
#pragma unroll
        for (int i = 0; i < 8; ++i) {
            size_t base = (size_t)row_a * 256 + i * 32 + kgrp;
            a[i] = *(const s16x8*)&hb[base];
        }
    }

    int st_col = tid >> 3;
    int st_kk = (tid & 7) * 32;
    int st_sw = (st_col & 7) << 4;
    int st_base = st_col * 512 + st_kk * 2;

    auto stage = [&](int buf, int t) {
        const s16x8* src = (const s16x8*)&WT[(size_t)(t * 32 + st_col) * 256 + st_kk];
        char* dst = (char*)bs[buf];
#pragma unroll
        for (int q = 0; q < 4; ++q)
            *(s16x8*)(dst + ((st_base + q * 16) ^ st_sw)) = src[q];
    };

    stage(0, 0);

    int col = lane & 15;
    int rd_base = col * 512 + (lane >> 4) * 16;
    int rd_sw = (col & 7) << 4;
    int rbase = m0 + (lane >> 4) * 4;

    for (int t = 0; t < 7; ++t) {
        __syncthreads();
        if (t + 1 < 7) stage((t + 1) & 1, t + 1);

        const char* base = (const char*)bs[t & 1];
        f32x4v c0 = {0.f, 0.f, 0.f, 0.f};
        f32x4v c1 = {0.f, 0.f, 0.f, 0.f};
#pragma unroll
        for (int i = 0; i < 8; ++i) {
            s16x8 b0 = *(const s16x8*)(base + ((rd_base + i * 64) ^ rd_sw));
            s16x8 b1 = *(const s16x8*)(base + ((rd_base + 8192 + i * 64) ^ rd_sw));
            c0 = __builtin_amdgcn_mfma_f32_16x16x32_bf16(a[i], b0, c0, 0, 0, 0);
            c1 = __builtin_amdgcn_mfma_f32_16x16x32_bf16(a[i], b1, c1, 0, 0, 0);
        }

        int cc0 = t * 32 + col;
        int cc1 = cc0 + 16;
        float cb0 = (cc0 >= 128) ? cb[cc0 - 128] : 0.f;
        float cb1 = (cc1 >= 128) ? cb[cc1 - 128] : 0.f;
#pragma unroll
        for (int r = 0; r < 4; ++r) {
            int row = rbase + r;
            if (row >= N) continue;
            float v0 = c0[r], v1 = c1[r];
            if (cc0 < 128) bases[(size_t)row * 128 + cc0] = f2b(v0);
            else wts[(size_t)row * 96 + (cc0 - 128)] = f2b(v0 + cb0);
            if (cc1 < 128) bases[(size_t)row * 128 + cc1] = f2b(v1);
            else wts[(size_t)row * 96 + (cc1 - 128)] = f2b(v1 + cb1);
        }
    }
}

// ---------------- Aggregation v7 (proven): 1 node/wave, 8B gathers, half-wave pairs ----------------
__global__ __launch_bounds__(256) void agg_einsum(const short* __restrict__ bases,
                                                  const short* __restrict__ wts,
                                                  const int* __restrict__ row_ptr,
                                                  const int* __restrict__ srcs,
                                                  const float* __restrict__ cbias,
                                                  short* __restrict__ outp,
                                                  float* __restrict__ partial, int N) {
    __shared__ float agg_lds[4][3][128];
    __shared__ float wts_lds[4][96];
    __shared__ float red[4][256];
    int wid = threadIdx.x >> 6;
    int lane = threadIdx.x & 63;
    int n = blockIdx.x * 4 + wid;
    bool valid = (n < N);

    int r0 = 0, r1 = 0;
    if (valid) {
        r0 = row_ptr[n];
        r1 = row_ptr[n + 1];
        wts_lds[wid][lane] = b2f(wts[(size_t)n * 96 + lane]);
        if (lane < 32) wts_lds[wid][64 + lane] = b2f(wts[(size_t)n * 96 + 64 + lane]);
    }

    int g = lane & 31;     // channel group: bf16 channels 4g..4g+3
    int half = lane >> 5;  // which edge of each pair
    const short* bp = bases + 4 * g;
    const float NI = -3.402823466e+38f;
    float sA0 = 0.f, sA1 = 0.f, sA2 = 0.f, sA3 = 0.f;
    float sB0 = 0.f, sB1 = 0.f, sB2 = 0.f, sB3 = 0.f;
    float mA0 = NI, mA1 = NI, mA2 = NI, mA3 = NI;
    float mB0 = NI, mB1 = NI, mB2 = NI, mB3 = NI;

#define GACC8(S, s0_, s1_, s2_, s3_, m0_, m1_, m2_, m3_)                     \
    {                                                                        \
        uint2 v = *(const uint2*)&bp[(size_t)(S) * 128];                     \
        float f0 = b2f_lo(v.x), f1 = b2f_hi(v.x);                            \
        float f2 = b2f_lo(v.y), f3 = b2f_hi(v.y);                            \
        s0_ += f0; s1_ += f1; s2_ += f2; s3_ += f3;                          \
        m0_ = fmaxf(m0_, f0); m1_ = fmaxf(m1_, f1);                          \
        m2_ = fmaxf(m2_, f2); m3_ = fmaxf(m3_, f3);                          \
    }

    int r = r0;
    while (r < r1) {
        int chunk = r1 - r;
        if (chunk > 64) chunk = 64;
        int sidx = (lane < chunk) ? srcs[r + lane] : 0;
        int npair = chunk >> 1;
        int jp = 0;
        for (; jp + 4 <= npair; jp += 4) {
            int e0 = (jp + 0) * 2 + half, e1 = (jp + 1) * 2 + half;
            int e2 = (jp + 2) * 2 + half, e3 = (jp + 3) * 2 + half;
            int s0 = __shfl(sidx, e0), s1 = __shfl(sidx, e1);
            int s2 = __shfl(sidx, e2), s3 = __shfl(sidx, e3);
            GACC8(s0, sA0, sA1, sA2, sA3, mA0, mA1, mA2, mA3);
            GACC8(s1, sB0, sB1, sB2, sB3, mB0, mB1, mB2, mB3);
            GACC8(s2, sA0, sA1, sA2, sA3, mA0, mA1, mA2, mA3);
            GACC8(s3, sB0, sB1, sB2, sB3, mB0, mB1, mB2, mB3);
        }
        for (; jp < npair; ++jp) {
            int e0 = jp * 2 + half;
            int s0 = __shfl(sidx, e0);
            GACC8(s0, sA0, sA1, sA2, sA3, mA0, mA1, mA2, mA3);
        }
        if (chunk & 1) {
            int s0 = __shfl(sidx, chunk - 1);
            if (half == 0) {
                GACC8(s0, sB0, sB1, sB2, sB3, mB0, mB1, mB2, mB3);
            }
        }
        r += chunk;
    }
#undef GACC8

    float accs[4] = {0.f, 0.f, 0.f, 0.f};
    if (valid) {
        float s0 = sA0 + sB0, s1 = sA1 + sB1, s2 = sA2 + sB2, s3 = sA3 + sB3;
        float m0 = fmaxf(mA0, mB0), m1 = fmaxf(mA1, mB1);
        float m2 = fmaxf(mA2, mB2), m3 = fmaxf(mA3, mB3);
        s0 += __shfl_xor(s0, 32); s1 += __shfl_xor(s1, 32);
        s2 += __shfl_xor(s2, 32); s3 += __shfl_xor(s3, 32);
        m0 = fmaxf(m0, __shfl_xor(m0, 32)); m1 = fmaxf(m1, __shfl_xor(m1, 32));
        m2 = fmaxf(m2, __shfl_xor(m2, 32)); m3 = fmaxf(m3, __shfl_xor(m3, 32));

        float inv = 1.0f / (float)(r1 - r0);
        if (half == 0) {
            float4 sv = make_float4(s0, s1, s2, s3);
            float4 mv = make_float4(s0 * inv, s1 * inv, s2 * inv, s3 * inv);
            float4 xv = make_float4(m0, m1, m2, m3);
            *(float4*)&agg_lds[wid][0][4 * g] = sv;
            *(float4*)&agg_lds[wid][1][4 * g] = mv;
            *(float4*)&agg_lds[wid][2][4 * g] = xv;
        }

        asm volatile("s_waitcnt lgkmcnt(0)" ::: "memory");

#pragma unroll
        for (int j = 0; j < 4; ++j) {
            int o = lane + 64 * j;
            int hh = o >> 5;
            int d = o & 31;
            float acc = cbias[o];
#pragma unroll
            for (int k = 0; k < 12; ++k)
                acc = fmaf(wts_lds[wid][hh * 12 + k], agg_lds[wid][k >> 2][(k & 3) * 32 + d], acc);
            outp[(size_t)n * 256 + o] = f2b(acc);
            accs[j] = acc;
        }
    }
    // block-level BN partial (deterministic, fp32 pre-rounding)
#pragma unroll
    for (int j = 0; j < 4; ++j) red[wid][lane + 64 * j] = accs[j];
    __syncthreads();
    int c = threadIdx.x;
    float s = (red[0][c] + red[1][c]) + (red[2][c] + red[3][c]);
    float s2 = (red[0][c] * red[0][c] + red[1][c] * red[1][c]) +
               (red[2][c] * red[2][c] + red[3][c] * red[3][c]);
    partial[((size_t)blockIdx.x * 2 + 0) * 256 + c] = s;
    partial[((size_t)blockIdx.x * 2 + 1) * 256 + c] = s2;
}

// ---------------- BN coalesced tree reduce: NB partials -> 256 partials ----------------
__global__ __launch_bounds__(256) void bn_reduce(const float* __restrict__ partial, int NB,
                                                 float* __restrict__ partial2) {
    int t = threadIdx.x;
    int chunk = (NB + 255) / 256;
    int rbeg = blockIdx.x * chunk;
    int rend = min(NB, rbeg + chunk);
    float s = 0.f, s2 = 0.f;
    for (int r = rbeg; r < rend; ++r) {
        s += partial[((size_t)r * 2 + 0) * 256 + t];
        s2 += partial[((size_t)r * 2 + 1) * 256 + t];
    }
    partial2[((size_t)blockIdx.x * 2 + 0) * 256 + t] = s;
    partial2[((size_t)blockIdx.x * 2 + 1) * 256 + t] = s2;
}

// ---------------- BN stats (generic, small inputs / MLP) ----------------
__global__ void bn_stats(const float* __restrict__ v, int N, int C, float* __restrict__ partial) {
    int c = threadIdx.x;  // blockDim == C
    float s = 0.f, s2 = 0.f;
    for (int r = blockIdx.x; r < N; r += gridDim.x) {
        float t = v[r * C + c];
        s += t; s2 += t * t;
    }
    partial[(blockIdx.x * 2 + 0) * C + c] = s;
    partial[(blockIdx.x * 2 + 1) * C + c] = s2;
}

// parallel finalize: one block per channel
__global__ __launch_bounds__(256) void bn_finalize(const float* __restrict__ partial, int NB, int C, int N,
                                                   const float* __restrict__ gamma, const float* __restrict__ beta,
                                                   float* __restrict__ ss) {
    int c = blockIdx.x;
    float s = 0.f, s2 = 0.f;
    for (int b = threadIdx.x; b < NB; b += 256) {
        s += partial[((size_t)b * 2 + 0) * C + c];
        s2 += partial[((size_t)b * 2 + 1) * C + c];
    }
#pragma unroll
    for (int off = 32; off > 0; off >>= 1) {
        s += __shfl_down(s, off);
        s2 += __shfl_down(s2, off);
    }
    __shared__ float wsum[4][2];
    int wid = threadIdx.x >> 6;
    int lane = threadIdx.x & 63;
    if (lane == 0) { wsum[wid][0] = s; wsum[wid][1] = s2; }
    __syncthreads();
    if (threadIdx.x == 0) {
        s = (wsum[0][0] + wsum[1][0]) + (wsum[2][0] + wsum[3][0]);
        s2 = (wsum[0][1] + wsum[1][1]) + (wsum[2][1] + wsum[3][1]);
        float invN = 1.0f / (float)N;
        float mu = s * invN;
        float var = fmaxf(s2 * invN - mu * mu, 0.f);
        float sc = gamma[c] * rsqrtf(var + 1e-5f);
        ss[c] = sc;
        ss[C + c] = beta[c] - mu * sc;
    }
}

// ---------------- Pool with fused final BN+residual ----------------
__device__ int lower_bound_dev(const int* a, int n, int v) {
    int lo = 0, hi = n;
    while (lo < hi) {
        int mid = (lo + hi) >> 1;
        if (a[mid] < v) lo = mid + 1; else hi = mid;
    }
    return lo;
}

__global__ __launch_bounds__(256) void pool_kernel(const short* __restrict__ hb,
                                                   const short* __restrict__ outb,
                                                   const float* __restrict__ ss,
                                                   const int* __restrict__ batch, int N,
                                                   float* __restrict__ g) {
    __shared__ int sh[2];
    if (threadIdx.x == 0) {
        sh[0] = lower_bound_dev(batch, N, (int)blockIdx.x);
        sh[1] = lower_bound_dev(batch, N, (int)blockIdx.x + 1);
    }
    __syncthreads();
    int s0 = sh[0], s1 = sh[1];
    int c = threadIdx.x;
    float sc = ss[c], shf = ss[256 + c];
    float s = 0.f;
    for (int r = s0; r < s1; ++r) {
        size_t idx = (size_t)r * 256 + c;
        float hf = b2f(hb[idx]) + fmaxf(b2f(outb[idx]) * sc + shf, 0.f);
        s += hf;
    }
    float cnt = (float)(s1 - s0);
    g[blockIdx.x * 256 + c] = s / fmaxf(cnt, 1.0f);
}

// ---------------- MLP ----------------
__global__ void mlp_gemm(const float* __restrict__ in, const float* __restrict__ W,
                         float* __restrict__ outp, int K, int C) {
    extern __shared__ float srow[];
    int r = blockIdx.x;
    for (int k = threadIdx.x; k < K; k += blockDim.x) srow[k] = in[r * K + k];
    __syncthreads();
    int c = threadIdx.x;
    float acc = 0.f;
    for (int k = 0; k < K; ++k) acc = fmaf(srow[k], W[k * C + c], acc);
    outp[r * C + c] = acc;
}

// same, but applies relu(in*sc+sh) with ssb[0:K]=scale, ssb[K:2K]=shift when staging
__global__ void mlp_gemm_bn(const float* __restrict__ in, const float* __restrict__ ssb,
                            const float* __restrict__ W,
                            float* __restrict__ outp, int K, int C) {
    extern __shared__ float srow[];
    int r = blockIdx.x;
    for (int k = threadIdx.x; k < K; k += blockDim.x)
        srow[k] = fmaxf(in[r * K + k] * ssb[k] + ssb[K + k], 0.f);
    __syncthreads();
    int c = threadIdx.x;
    float acc = 0.f;
    for (int k = 0; k < K; ++k) acc = fmaf(srow[k], W[k * C + c], acc);
    outp[r * C + c] = acc;
}

__global__ void final_gemm_bn(const float* __restrict__ z2, const float* __restrict__ ssb,
                              const float* __restrict__ w3,
                              const float* __restrict__ b3, float* __restrict__ outp, int G) {
    int g = blockIdx.x * blockDim.x + threadIdx.x;
    if (g >= G) return;
    float acc = b3[0];
    for (int k = 0; k < 64; ++k) {
        float z = fmaxf(z2[g * 64 + k] * ssb[k] + ssb[64 + k], 0.f);
        acc = fmaf(z, w3[k], acc);
    }
    outp[g] = acc;
}

extern "C" void kernel_launch(void* const* d_in, const int* in_sizes, int n_in,
                              void* d_out, int out_size, void* d_ws, size_t ws_size,
                              hipStream_t stream) {
    const float* atom_emb = (const float*)d_in[0];
    const float* bases_W = (const float*)d_in[1];
    const float* comb_W = (const float*)d_in[2];
    const float* comb_b = (const float*)d_in[3];
    const float* conv_bias = (const float*)d_in[4];
    const float* bn_gamma = (const float*)d_in[5];
    const float* bn_beta = (const float*)d_in[6];
    const float* w1 = (const float*)d_in[7];
    const float* g1 = (const float*)d_in[8];
    const float* b1 = (const float*)d_in[9];
    const float* w2 = (const float*)d_in[10];
    const float* g2 = (const float*)d_in[11];
    const float* b2 = (const float*)d_in[12];
    const float* w3 = (const float*)d_in[13];
    const float* b3 = (const float*)d_in[14];
    const int* x = (const int*)d_in[15];
    const int* edge_index = (const int*)d_in[16];
    const int* batch = (const int*)d_in[17];
    float* out = (float*)d_out;

    const int N = in_sizes[15] / 9;
    const int E = in_sizes[16] / 2;
    const int G = NGRAPH;
    const int T = E + N;
    const int NCHUNK = (N + 1023) / 1024;
    const int PB = (T + 4095) / 4096;        // phase blocks
    const int NBK = (N + 255) >> 8;          // dst buckets (<=256)
    const int M = NBK * PB;                  // histogram matrix size
    const int MCHUNK = (M + 1023) / 1024;
    const int AGG_NB = (N + 3) / 4;          // agg grid / BN partial count

    // workspace carve
    char* p = (char*)d_ws;
    auto alloc = [&](size_t bytes) -> void* {
        void* r = (void*)p;
        p += (bytes + 255) & ~(size_t)255;
        return r;
    };
    short* hb = (short*)alloc((size_t)N * 256 * 2);
    short* outb = (short*)alloc((size_t)N * 256 * 2);
    short* bases = (short*)alloc((size_t)N * 128 * 2);
    short* wts = (short*)alloc((size_t)N * 96 * 2);
    short* WT = (short*)alloc((size_t)4 * 224 * 256 * 2);
    int* row_ptr = (int*)alloc((size_t)(N + 1) * 4);
    int* cnt = (int*)alloc((size_t)N * 4);
    int* woff = (int*)alloc((size_t)N * 4);
    int* blksum = (int*)alloc((size_t)256 * 4);
    int* mcnt = (int*)alloc((size_t)(M + 1) * 4);
    int* moff = (int*)alloc((size_t)(M + 1) * 4);
    int* srcs = (int*)alloc((size_t)T * 4);
    float* partial = (float*)alloc((size_t)AGG_NB * 2 * 256 * 4);
    float* partial2 = (float*)alloc((size_t)256 * 2 * 256 * 4);
    float* ss = (float*)alloc((size_t)2 * 256 * 4);
    float* g = (float*)alloc((size_t)G * 256 * 4);
    float* z1 = (float*)alloc((size_t)G * 128 * 4);
    float* z2 = (float*)alloc((size_t)G * 64 * 4);
    uint2* pairs = (uint2*)alloc((size_t)T * 8);

    // atom encoder + weight prep
    atom_enc<<<N, 256, 0, stream>>>(x, atom_emb, hb, N);
    prep_wt<<<4 * 224, 256, 0, stream>>>(bases_W, comb_W, WT);

    // CSR row_ptr (self-loop via addone=1 in scans)
    hipMemsetAsync(cnt, 0, (size_t)N * 4, stream);
    csr_count<<<(E + 255) / 256, 256, 0, stream>>>(edge_index, E, cnt);
    scan_s1<<<NCHUNK, 256, 0, stream>>>(cnt, blksum, N, 1);
    scan_s2<<<1, 256, 0, stream>>>(blksum, NCHUNK, row_ptr, N);
    scan_s3<<<NCHUNK, 256, 0, stream>>>(cnt, blksum, row_ptr, woff, N, 1);

    // bucketed edge sort
    ph_hist<<<PB, 256, 0, stream>>>(edge_index, E, T, PB, NBK, mcnt);
    scan_s1<<<MCHUNK, 256, 0, stream>>>(mcnt, blksum, M, 0);
    scan_s2<<<1, 256, 0, stream>>>(blksum, MCHUNK, moff, M);
    scan_s3<<<MCHUNK, 256, 0, stream>>>(mcnt, blksum, moff, moff, M, 0);
    ph_scatter<<<PB, 256, 0, stream>>>(edge_index, E, T, PB, NBK, moff, pairs);
    ph_sort<<<NBK, 256, 0, stream>>>(pairs, row_ptr, moff, NBK, PB, T, srcs);

    for (int l = 0; l < 4; ++l) {
        const short* WTl = WT + (size_t)l * 224 * 256;
        const float* cb = comb_b + (size_t)l * 96;
        const float* cbias = conv_bias + (size_t)l * 256;
        const float* gam = bn_gamma + (size_t)l * 256;
        const float* bet = bn_beta + (size_t)l * 256;

        // BN-apply of previous layer fused into GEMM input path
        gemm_mfma<<<(N + 63) / 64, 256, 0, stream>>>(hb, outb, ss, l > 0 ? 1 : 0,
                                                     WTl, cb, bases, wts, N);
        agg_einsum<<<AGG_NB, 256, 0, stream>>>(bases, wts, row_ptr, srcs, cbias, outb, partial, N);
        bn_reduce<<<256, 256, 0, stream>>>(partial, AGG_NB, partial2);
        bn_finalize<<<256, 256, 0, stream>>>(partial2, 256, 256, N, gam, bet, ss);
    }

    // pool with fused layer-4 BN+residual
    pool_kernel<<<G, 256, 0, stream>>>(hb, outb, ss, batch, N, g);

    // MLP layer 1: 256 -> 128
    mlp_gemm<<<G, 128, 256 * 4, stream>>>(g, w1, z1, 256, 128);
    bn_stats<<<64, 128, 0, stream>>>(z1, G, 128, partial);
    bn_finalize<<<128, 256, 0, stream>>>(partial, 64, 128, G, g1, b1, ss);

    // MLP layer 2: 128 -> 64 (BN1 applied on input staging)
    mlp_gemm_bn<<<G, 64, 128 * 4, stream>>>(z1, ss, w2, z2, 128, 64);
    bn_stats<<<64, 64, 0, stream>>>(z2, G, 64, partial);
    bn_finalize<<<64, 256, 0, stream>>>(partial, 64, 64, G, g2, b2, ss);

    // final: 64 -> 1 (BN2 applied inline)
    final_gemm_bn<<<(G + 255) / 256, 256, 0, stream>>>(z2, ss, w3, b3, out, G);
}

// Round 16
// 547.294 us; speedup vs baseline: 1.0025x; 1.0025x over previous
//
#include <hip/hip_runtime.h>
#include <hip/hip_bf16.h>

#define HID 256
#define NGRAPH 2048

typedef __attribute__((ext_vector_type(8))) short s16x8;
typedef __attribute__((ext_vector_type(4))) float f32x4v;

__device__ inline short f2b(float f) {
    __hip_bfloat16 b = __float2bfloat16(f);
    return *reinterpret_cast<short*>(&b);
}
__device__ inline float b2f(short s) {
    return __uint_as_float(((unsigned)(unsigned short)s) << 16);
}
__device__ inline float b2f_lo(unsigned int v) {
    return __uint_as_float(v << 16);
}
__device__ inline float b2f_hi(unsigned int v) {
    return __uint_as_float(v & 0xffff0000u);
}

// ---------------- Atom encoder: 4 nodes/block, wave per node ----------------
__global__ __launch_bounds__(256) void atom_enc(const int* __restrict__ x,
                                                const float* __restrict__ emb,
                                                short* __restrict__ hb, int N) {
    int wid = threadIdx.x >> 6;
    int lane = threadIdx.x & 63;
    int n = blockIdx.x * 4 + wid;
    if (n >= N) return;
    const int offs[9] = {0, 119, 124, 136, 148, 158, 164, 170, 172};
    float s0 = 0.f, s1 = 0.f, s2 = 0.f, s3 = 0.f;
#pragma unroll
    for (int j = 0; j < 9; ++j) {
        int row = x[n * 9 + j] + offs[j];
        float4 v = *(const float4*)&emb[(size_t)row * 256 + 4 * lane];
        s0 += v.x; s1 += v.y; s2 += v.z; s3 += v.w;
    }
    short4 o;
    o.x = f2b(s0); o.y = f2b(s1); o.z = f2b(s2); o.w = f2b(s3);
    *(short4*)&hb[(size_t)n * 256 + 4 * lane] = o;
}

// ---------------- Weight prep ----------------
__global__ void prep_wt(const float* __restrict__ bases_W, const float* __restrict__ comb_W,
                        short* __restrict__ WT) {
    int l = blockIdx.x / 224;
    int n = blockIdx.x % 224;
    int k = threadIdx.x;  // 0..255
    float v = (n < 128) ? bases_W[((size_t)l * 256 + k) * 128 + n]
                        : comb_W[((size_t)l * 256 + k) * 96 + (n - 128)];
    WT[((size_t)l * 224 + n) * 256 + k] = f2b(v);
}

// hierarchical scan: S1 per-1024-chunk sums (addone: +1/elem for self-loops)
__global__ __launch_bounds__(256) void scan_s1(const int* __restrict__ cnt, int* __restrict__ blksum,
                                               int N, int addone) {
    __shared__ int red[256];
    int base = blockIdx.x * 1024;
    int s = 0;
#pragma unroll
    for (int q = 0; q < 4; ++q) {
        int i = base + threadIdx.x * 4 + q;
        s += (i < N) ? (cnt[i] + addone) : 0;
    }
    red[threadIdx.x] = s;
    __syncthreads();
    for (int off = 128; off > 0; off >>= 1) {
        if (threadIdx.x < off) red[threadIdx.x] += red[threadIdx.x + off];
        __syncthreads();
    }
    if (threadIdx.x == 0) blksum[blockIdx.x] = red[0];
}

// S2: exclusive scan of block sums (nb <= 256), writes total to row_ptr[N]
__global__ __launch_bounds__(256) void scan_s2(int* __restrict__ blksum, int nb, int* __restrict__ row_ptr, int N) {
    __shared__ int buf[256];
    int v = (threadIdx.x < nb) ? blksum[threadIdx.x] : 0;
    buf[threadIdx.x] = v;
    __syncthreads();
    for (int off = 1; off < 256; off <<= 1) {
        int t = (threadIdx.x >= off) ? buf[threadIdx.x - off] : 0;
        __syncthreads();
        buf[threadIdx.x] += t;
        __syncthreads();
    }
    if (threadIdx.x < nb) blksum[threadIdx.x] = buf[threadIdx.x] - v;  // exclusive
    if (threadIdx.x == 0) row_ptr[N] = buf[255];
}

// S3: per-chunk local scan + base; writes two copies (row_ptr, woff)
__global__ __launch_bounds__(256) void scan_s3(const int* __restrict__ cnt, const int* __restrict__ blksum,
                                               int* __restrict__ row_ptr, int* __restrict__ woff,
                                               int N, int addone) {
    __shared__ int buf[256];
    int base = blockIdx.x * 1024;
    int i0 = base + threadIdx.x * 4;
    int v[4];
    int s = 0;
#pragma unroll
    for (int q = 0; q < 4; ++q) {
        int i = i0 + q;
        v[q] = (i < N) ? (cnt[i] + addone) : 0;
        s += v[q];
    }
    buf[threadIdx.x] = s;
    __syncthreads();
    for (int off = 1; off < 256; off <<= 1) {
        int t = (threadIdx.x >= off) ? buf[threadIdx.x - off] : 0;
        __syncthreads();
        buf[threadIdx.x] += t;
        __syncthreads();
    }
    int excl = buf[threadIdx.x] - s + blksum[blockIdx.x];
#pragma unroll
    for (int q = 0; q < 4; ++q) {
        int i = i0 + q;
        if (i < N) { row_ptr[i] = excl; woff[i] = excl; }
        excl += v[q];
    }
}

// ---------------- Fused per-node count + bucketed histogram ----------------
// global cnt[d]++ for real edges; LDS histogram of dst>>8 for all T (incl self-loops)
__global__ __launch_bounds__(256) void ph_hist(const int* __restrict__ ei, int E, int T,
                                               int PB, int NBK, int* __restrict__ mcnt,
                                               int* __restrict__ cnt) {
    __shared__ int hist[256];
    hist[threadIdx.x] = 0;
    __syncthreads();
    int base = blockIdx.x * 4096;
#pragma unroll
    for (int q = 0; q < 16; ++q) {
        int i = base + q * 256 + threadIdx.x;
        if (i < T) {
            int d = (i < E) ? ei[i] : (i - E);
            atomicAdd(&hist[d >> 8], 1);
            if (i < E) atomicAdd(&cnt[d], 1);
        }
    }
    __syncthreads();
    if (threadIdx.x < NBK) mcnt[threadIdx.x * PB + blockIdx.x] = hist[threadIdx.x];
}

__global__ __launch_bounds__(256) void ph_scatter(const int* __restrict__ ei, int E, int T,
                                                  int PB, int NBK, const int* __restrict__ moff,
                                                  uint2* __restrict__ pairs) {
    __shared__ int off[256];
    if (threadIdx.x < NBK) off[threadIdx.x] = moff[threadIdx.x * PB + blockIdx.x];
    __syncthreads();
    int base = blockIdx.x * 4096;
#pragma unroll
    for (int q = 0; q < 16; ++q) {
        int i = base + q * 256 + threadIdx.x;
        if (i < T) {
            int d, s;
            if (i < E) { d = ei[i]; s = ei[E + i]; }
            else       { d = i - E; s = i - E; }
            int pos = atomicAdd(&off[d >> 8], 1);
            pairs[pos] = make_uint2((unsigned)d, (unsigned)s);
        }
    }
}

__global__ __launch_bounds__(256) void ph_sort(const uint2* __restrict__ pairs,
                                               const int* __restrict__ row_ptr,
                                               const int* __restrict__ moff,
                                               int NBK, int PB, int T,
                                               int* __restrict__ srcs) {
    __shared__ int wcnt[256];
    wcnt[threadIdx.x] = 0;
    __syncthreads();
    int bin = blockIdx.x;
    int p0 = moff[bin * PB];
    int p1 = (bin + 1 < NBK) ? moff[(bin + 1) * PB] : T;
    for (int i = p0 + threadIdx.x; i < p1; i += 256) {
        uint2 u = pairs[i];
        int d = (int)u.x;
        int rank = atomicAdd(&wcnt[d & 255], 1);
        srcs[row_ptr[d] + rank] = (int)u.y;
    }
}

// ---------------- MFMA GEMM, fused BN-apply+residual, all-bf16 h/outb/wts ----------------
__global__ __launch_bounds__(256) void gemm_mfma(short* hb,
                                                 const short* __restrict__ outb,
                                                 const float* __restrict__ ss,
                                                 int do_bn,
                                                 const short* __restrict__ WT,
                                                 const float* __restrict__ cb,
                                                 short* __restrict__ bases,
                                                 short* __restrict__ wts, int N) {
    __shared__ short bs[2][32 * 256];  // 2 x 16KB
    int tid = threadIdx.x;
    int wid = tid >> 6;
    int lane = tid & 63;
    int m0 = blockIdx.x * 64 + wid * 16;
    int row_orig = m0 + (lane & 15);
    bool owner = (row_orig < N);
    int row_a = owner ? row_orig : (N - 1);
    int kgrp = (lane >> 4) * 8;  // 0,8,16,24

    s16x8 a[8];
    if (do_bn) {
#pragma unroll
        for (int i = 0; i < 8; ++i) {
            int cbase = i * 32 + kgrp;
            size_t base = (size_t)row_a * 256 + cbase;
            s16x8 hv = *(const s16x8*)&hb[base];
            s16x8 ov = *(const s16x8*)&outb[base];
            s16x8 t;
#pragma unroll
            for (int k = 0; k < 8; ++k) {
                float hf = b2f(hv[k]);
                float of = b2f(ov[k]);
                float sc = ss[cbase + k];
                float sh = ss[256 + cbase + k];
                hf += fmaxf(of * sc + sh, 0.f);
                t[k] = f2b(hf);
            }
            if (owner) *(s16x8*)&hb[base] = t;
            a[i] = t;
        }
    } else {
#pragma unroll
        for (int i = 0; i < 8; ++i) {
            size_t base = (size_t)row_a * 256 + i * 32 + kgrp;
            a[i] = *(const s16x8*)&hb[base];
        }
    }

    int st_col = tid >> 3;
    int st_kk = (tid & 7) * 32;
    int st_sw = (st_col & 7) << 4;
    int st_base = st_col * 512 + st_kk * 2;

    auto stage = [&](int buf, int t) {
        const s16x8* src = (const s16x8*)&WT[(size_t)(t * 32 + st_col) * 256 + st_kk];
        char* dst = (char*)bs[buf];
#pragma unroll
        for (int q = 0; q < 4; ++q)
            *(s16x8*)(dst + ((st_base + q * 16) ^ st_sw)) = src[q];
    };

    stage(0, 0);

    int col = lane & 15;
    int rd_base = col * 512 + (lane >> 4) * 16;
    int rd_sw = (col & 7) << 4;
    int rbase = m0 + (lane >> 4) * 4;

    for (int t = 0; t < 7; ++t) {
        __syncthreads();
        if (t + 1 < 7) stage((t + 1) & 1, t + 1);

        const char* base = (const char*)bs[t & 1];
        f32x4v c0 = {0.f, 0.f, 0.f, 0.f};
        f32x4v c1 = {0.f, 0.f, 0.f, 0.f};
#pragma unroll
        for (int i = 0; i < 8; ++i) {
            s16x8 b0 = *(const s16x8*)(base + ((rd_base + i * 64) ^ rd_sw));
            s16x8 b1 = *(const s16x8*)(base + ((rd_base + 8192 + i * 64) ^ rd_sw));
            c0 = __builtin_amdgcn_mfma_f32_16x16x32_bf16(a[i], b0, c0, 0, 0, 0);
            c1 = __builtin_amdgcn_mfma_f32_16x16x32_bf16(a[i], b1, c1, 0, 0, 0);
        }

        int cc0 = t * 32 + col;
        int cc1 = cc0 + 16;
        float cb0 = (cc0 >= 128) ? cb[cc0 - 128] : 0.f;
        float cb1 = (cc1 >= 128) ? cb[cc1 - 128] : 0.f;
#pragma unroll
        for (int r = 0; r < 4; ++r) {
            int row = rbase + r;
            if (row >= N) continue;
            float v0 = c0[r], v1 = c1[r];
            if (cc0 < 128) bases[(size_t)row * 128 + cc0] = f2b(v0);
            else wts[(size_t)row * 96 + (cc0 - 128)] = f2b(v0 + cb0);
            if (cc1 < 128) bases[(size_t)row * 128 + cc1] = f2b(v1);
            else wts[(size_t)row * 96 + (cc1 - 128)] = f2b(v1 + cb1);
        }
    }
}

// ---------------- Aggregation v9: v7 structure, 4 accumulator sets (8 loads in flight) ----------------
__global__ __launch_bounds__(256) void agg_einsum(const short* __restrict__ bases,
                                                  const short* __restrict__ wts,
                                                  const int* __restrict__ row_ptr,
                                                  const int* __restrict__ srcs,
                                                  const float* __restrict__ cbias,
                                                  short* __restrict__ outp,
                                                  float* __restrict__ partial, int N) {
    __shared__ float agg_lds[4][3][128];
    __shared__ float wts_lds[4][96];
    __shared__ float red[4][256];
    int wid = threadIdx.x >> 6;
    int lane = threadIdx.x & 63;
    int n = blockIdx.x * 4 + wid;
    bool valid = (n < N);

    int r0 = 0, r1 = 0;
    if (valid) {
        r0 = row_ptr[n];
        r1 = row_ptr[n + 1];
        wts_lds[wid][lane] = b2f(wts[(size_t)n * 96 + lane]);
        if (lane < 32) wts_lds[wid][64 + lane] = b2f(wts[(size_t)n * 96 + 64 + lane]);
    }

    int g = lane & 31;     // channel group: bf16 channels 4g..4g+3
    int half = lane >> 5;  // which edge of each pair
    const short* bp = bases + 4 * g;
    const float NI = -3.402823466e+38f;
    float sA0 = 0.f, sA1 = 0.f, sA2 = 0.f, sA3 = 0.f;
    float sB0 = 0.f, sB1 = 0.f, sB2 = 0.f, sB3 = 0.f;
    float sC0 = 0.f, sC1 = 0.f, sC2 = 0.f, sC3 = 0.f;
    float sD0 = 0.f, sD1 = 0.f, sD2 = 0.f, sD3 = 0.f;
    float mA0 = NI, mA1 = NI, mA2 = NI, mA3 = NI;
    float mB0 = NI, mB1 = NI, mB2 = NI, mB3 = NI;
    float mC0 = NI, mC1 = NI, mC2 = NI, mC3 = NI;
    float mD0 = NI, mD1 = NI, mD2 = NI, mD3 = NI;

#define GACC8(S, s0_, s1_, s2_, s3_, m0_, m1_, m2_, m3_)                     \
    {                                                                        \
        uint2 v = *(const uint2*)&bp[(size_t)(S) * 128];                     \
        float f0 = b2f_lo(v.x), f1 = b2f_hi(v.x);                            \
        float f2 = b2f_lo(v.y), f3 = b2f_hi(v.y);                            \
        s0_ += f0; s1_ += f1; s2_ += f2; s3_ += f3;                          \
        m0_ = fmaxf(m0_, f0); m1_ = fmaxf(m1_, f1);                          \
        m2_ = fmaxf(m2_, f2); m3_ = fmaxf(m3_, f3);                          \
    }

    int r = r0;
    while (r < r1) {
        int chunk = r1 - r;
        if (chunk > 64) chunk = 64;
        int sidx = (lane < chunk) ? srcs[r + lane] : 0;
        int npair = chunk >> 1;
        int jp = 0;
        for (; jp + 4 <= npair; jp += 4) {
            int e0 = (jp + 0) * 2 + half, e1 = (jp + 1) * 2 + half;
            int e2 = (jp + 2) * 2 + half, e3 = (jp + 3) * 2 + half;
            int s0 = __shfl(sidx, e0), s1 = __shfl(sidx, e1);
            int s2 = __shfl(sidx, e2), s3 = __shfl(sidx, e3);
            GACC8(s0, sA0, sA1, sA2, sA3, mA0, mA1, mA2, mA3);
            GACC8(s1, sB0, sB1, sB2, sB3, mB0, mB1, mB2, mB3);
            GACC8(s2, sC0, sC1, sC2, sC3, mC0, mC1, mC2, mC3);
            GACC8(s3, sD0, sD1, sD2, sD3, mD0, mD1, mD2, mD3);
        }
        for (; jp < npair; ++jp) {
            int e0 = jp * 2 + half;
            int s0 = __shfl(sidx, e0);
            GACC8(s0, sA0, sA1, sA2, sA3, mA0, mA1, mA2, mA3);
        }
        if (chunk & 1) {
            int s0 = __shfl(sidx, chunk - 1);
            if (half == 0) {
                GACC8(s0, sB0, sB1, sB2, sB3, mB0, mB1, mB2, mB3);
            }
        }
        r += chunk;
    }
#undef GACC8

    float accs[4] = {0.f, 0.f, 0.f, 0.f};
    if (valid) {
        float s0 = (sA0 + sB0) + (sC0 + sD0);
        float s1 = (sA1 + sB1) + (sC1 + sD1);
        float s2 = (sA2 + sB2) + (sC2 + sD2);
        float s3 = (sA3 + sB3) + (sC3 + sD3);
        float m0 = fmaxf(fmaxf(mA0, mB0), fmaxf(mC0, mD0));
        float m1 = fmaxf(fmaxf(mA1, mB1), fmaxf(mC1, mD1));
        float m2 = fmaxf(fmaxf(mA2, mB2), fmaxf(mC2, mD2));
        float m3 = fmaxf(fmaxf(mA3, mB3), fmaxf(mC3, mD3));
        s0 += __shfl_xor(s0, 32); s1 += __shfl_xor(s1, 32);
        s2 += __shfl_xor(s2, 32); s3 += __shfl_xor(s3, 32);
        m0 = fmaxf(m0, __shfl_xor(m0, 32)); m1 = fmaxf(m1, __shfl_xor(m1, 32));
        m2 = fmaxf(m2, __shfl_xor(m2, 32)); m3 = fmaxf(m3, __shfl_xor(m3, 32));

        float inv = 1.0f / (float)(r1 - r0);
        if (half == 0) {
            float4 sv = make_float4(s0, s1, s2, s3);
            float4 mv = make_float4(s0 * inv, s1 * inv, s2 * inv, s3 * inv);
            float4 xv = make_float4(m0, m1, m2, m3);
            *(float4*)&agg_lds[wid][0][4 * g] = sv;
            *(float4*)&agg_lds[wid][1][4 * g] = mv;
            *(float4*)&agg_lds[wid][2][4 * g] = xv;
        }

        asm volatile("s_waitcnt lgkmcnt(0)" ::: "memory");

#pragma unroll
        for (int j = 0; j < 4; ++j) {
            int o = lane + 64 * j;
            int hh = o >> 5;
            int d = o & 31;
            float acc = cbias[o];
#pragma unroll
            for (int k = 0; k < 12; ++k)
                acc = fmaf(wts_lds[wid][hh * 12 + k], agg_lds[wid][k >> 2][(k & 3) * 32 + d], acc);
            outp[(size_t)n * 256 + o] = f2b(acc);
            accs[j] = acc;
        }
    }
    // block-level BN partial (deterministic, fp32 pre-rounding)
#pragma unroll
    for (int j = 0; j < 4; ++j) red[wid][lane + 64 * j] = accs[j];
    __syncthreads();
    int c = threadIdx.x;
    float s = (red[0][c] + red[1][c]) + (red[2][c] + red[3][c]);
    float s2 = (red[0][c] * red[0][c] + red[1][c] * red[1][c]) +
               (red[2][c] * red[2][c] + red[3][c] * red[3][c]);
    partial[((size_t)blockIdx.x * 2 + 0) * 256 + c] = s;
    partial[((size_t)blockIdx.x * 2 + 1) * 256 + c] = s2;
}

// ---------------- BN coalesced tree reduce: NB partials -> 256 partials ----------------
__global__ __launch_bounds__(256) void bn_reduce(const float* __restrict__ partial, int NB,
                                                 float* __restrict__ partial2) {
    int t = threadIdx.x;
    int chunk = (NB + 255) / 256;
    int rbeg = blockIdx.x * chunk;
    int rend = min(NB, rbeg + chunk);
    float s = 0.f, s2 = 0.f;
    for (int r = rbeg; r < rend; ++r) {
        s += partial[((size_t)r * 2 + 0) * 256 + t];
        s2 += partial[((size_t)r * 2 + 1) * 256 + t];
    }
    partial2[((size_t)blockIdx.x * 2 + 0) * 256 + t] = s;
    partial2[((size_t)blockIdx.x * 2 + 1) * 256 + t] = s2;
}

// ---------------- BN stats (generic, small inputs / MLP) ----------------
__global__ void bn_stats(const float* __restrict__ v, int N, int C, float* __restrict__ partial) {
    int c = threadIdx.x;  // blockDim == C
    float s = 0.f, s2 = 0.f;
    for (int r = blockIdx.x; r < N; r += gridDim.x) {
        float t = v[r * C + c];
        s += t; s2 += t * t;
    }
    partial[(blockIdx.x * 2 + 0) * C + c] = s;
    partial[(blockIdx.x * 2 + 1) * C + c] = s2;
}

// parallel finalize: one block per channel
__global__ __launch_bounds__(256) void bn_finalize(const float* __restrict__ partial, int NB, int C, int N,
                                                   const float* __restrict__ gamma, const float* __restrict__ beta,
                                                   float* __restrict__ ss) {
    int c = blockIdx.x;
    float s = 0.f, s2 = 0.f;
    for (int b = threadIdx.x; b < NB; b += 256) {
        s += partial[((size_t)b * 2 + 0) * C + c];
        s2 += partial[((size_t)b * 2 + 1) * C + c];
    }
#pragma unroll
    for (int off = 32; off > 0; off >>= 1) {
        s += __shfl_down(s, off);
        s2 += __shfl_down(s2, off);
    }
    __shared__ float wsum[4][2];
    int wid = threadIdx.x >> 6;
    int lane = threadIdx.x & 63;
    if (lane == 0) { wsum[wid][0] = s; wsum[wid][1] = s2; }
    __syncthreads();
    if (threadIdx.x == 0) {
        s = (wsum[0][0] + wsum[1][0]) + (wsum[2][0] + wsum[3][0]);
        s2 = (wsum[0][1] + wsum[1][1]) + (wsum[2][1] + wsum[3][1]);
        float invN = 1.0f / (float)N;
        float mu = s * invN;
        float var = fmaxf(s2 * invN - mu * mu, 0.f);
        float sc = gamma[c] * rsqrtf(var + 1e-5f);
        ss[c] = sc;
        ss[C + c] = beta[c] - mu * sc;
    }
}

// ---------------- Pool with fused final BN+residual ----------------
__device__ int lower_bound_dev(const int* a, int n, int v) {
    int lo = 0, hi = n;
    while (lo < hi) {
        int mid = (lo + hi) >> 1;
        if (a[mid] < v) lo = mid + 1; else hi = mid;
    }
    return lo;
}

__global__ __launch_bounds__(256) void pool_kernel(const short* __restrict__ hb,
                                                   const short* __restrict__ outb,
                                                   const float* __restrict__ ss,
                                                   const int* __restrict__ batch, int N,
                                                   float* __restrict__ g) {
    __shared__ int sh[2];
    if (threadIdx.x == 0) {
        sh[0] = lower_bound_dev(batch, N, (int)blockIdx.x);
        sh[1] = lower_bound_dev(batch, N, (int)blockIdx.x + 1);
    }
    __syncthreads();
    int s0 = sh[0], s1 = sh[1];
    int c = threadIdx.x;
    float sc = ss[c], shf = ss[256 + c];
    float s = 0.f;
    for (int r = s0; r < s1; ++r) {
        size_t idx = (size_t)r * 256 + c;
        float hf = b2f(hb[idx]) + fmaxf(b2f(outb[idx]) * sc + shf, 0.f);
        s += hf;
    }
    float cnt = (float)(s1 - s0);
    g[blockIdx.x * 256 + c] = s / fmaxf(cnt, 1.0f);
}

// ---------------- MLP ----------------
__global__ void mlp_gemm(const float* __restrict__ in, const float* __restrict__ W,
                         float* __restrict__ outp, int K, int C) {
    extern __shared__ float srow[];
    int r = blockIdx.x;
    for (int k = threadIdx.x; k < K; k += blockDim.x) srow[k] = in[r * K + k];
    __syncthreads();
    int c = threadIdx.x;
    float acc = 0.f;
    for (int k = 0; k < K; ++k) acc = fmaf(srow[k], W[k * C + c], acc);
    outp[r * C + c] = acc;
}

// same, but applies relu(in*sc+sh) with ssb[0:K]=scale, ssb[K:2K]=shift when staging
__global__ void mlp_gemm_bn(const float* __restrict__ in, const float* __restrict__ ssb,
                            const float* __restrict__ W,
                            float* __restrict__ outp, int K, int C) {
    extern __shared__ float srow[];
    int r = blockIdx.x;
    for (int k = threadIdx.x; k < K; k += blockDim.x)
        srow[k] = fmaxf(in[r * K + k] * ssb[k] + ssb[K + k], 0.f);
    __syncthreads();
    int c = threadIdx.x;
    float acc = 0.f;
    for (int k = 0; k < K; ++k) acc = fmaf(srow[k], W[k * C + c], acc);
    outp[r * C + c] = acc;
}

__global__ void final_gemm_bn(const float* __restrict__ z2, const float* __restrict__ ssb,
                              const float* __restrict__ w3,
                              const float* __restrict__ b3, float* __restrict__ outp, int G) {
    int g = blockIdx.x * blockDim.x + threadIdx.x;
    if (g >= G) return;
    float acc = b3[0];
    for (int k = 0; k < 64; ++k) {
        float z = fmaxf(z2[g * 64 + k] * ssb[k] + ssb[64 + k], 0.f);
        acc = fmaf(z, w3[k], acc);
    }
    outp[g] = acc;
}

extern "C" void kernel_launch(void* const* d_in, const int* in_sizes, int n_in,
                              void* d_out, int out_size, void* d_ws, size_t ws_size,
                              hipStream_t stream) {
    const float* atom_emb = (const float*)d_in[0];
    const float* bases_W = (const float*)d_in[1];
    const float* comb_W = (const float*)d_in[2];
    const float* comb_b = (const float*)d_in[3];
    const float* conv_bias = (const float*)d_in[4];
    const float* bn_gamma = (const float*)d_in[5];
    const float* bn_beta = (const float*)d_in[6];
    const float* w1 = (const float*)d_in[7];
    const float* g1 = (const float*)d_in[8];
    const float* b1 = (const float*)d_in[9];
    const float* w2 = (const float*)d_in[10];
    const float* g2 = (const float*)d_in[11];
    const float* b2 = (const float*)d_in[12];
    const float* w3 = (const float*)d_in[13];
    const float* b3 = (const float*)d_in[14];
    const int* x = (const int*)d_in[15];
    const int* edge_index = (const int*)d_in[16];
    const int* batch = (const int*)d_in[17];
    float* out = (float*)d_out;

    const int N = in_sizes[15] / 9;
    const int E = in_sizes[16] / 2;
    const int G = NGRAPH;
    const int T = E + N;
    const int NCHUNK = (N + 1023) / 1024;
    const int PB = (T + 4095) / 4096;        // phase blocks
    const int NBK = (N + 255) >> 8;          // dst buckets (<=256)
    const int M = NBK * PB;                  // histogram matrix size
    const int MCHUNK = (M + 1023) / 1024;
    const int AGG_NB = (N + 3) / 4;          // agg grid / BN partial count

    // workspace carve
    char* p = (char*)d_ws;
    auto alloc = [&](size_t bytes) -> void* {
        void* r = (void*)p;
        p += (bytes + 255) & ~(size_t)255;
        return r;
    };
    short* hb = (short*)alloc((size_t)N * 256 * 2);
    short* outb = (short*)alloc((size_t)N * 256 * 2);
    short* bases = (short*)alloc((size_t)N * 128 * 2);
    short* wts = (short*)alloc((size_t)N * 96 * 2);
    short* WT = (short*)alloc((size_t)4 * 224 * 256 * 2);
    int* row_ptr = (int*)alloc((size_t)(N + 1) * 4);
    int* cnt = (int*)alloc((size_t)N * 4);
    int* woff = (int*)alloc((size_t)N * 4);
    int* blksum = (int*)alloc((size_t)256 * 4);
    int* mcnt = (int*)alloc((size_t)(M + 1) * 4);
    int* moff = (int*)alloc((size_t)(M + 1) * 4);
    int* srcs = (int*)alloc((size_t)T * 4);
    float* partial = (float*)alloc((size_t)AGG_NB * 2 * 256 * 4);
    float* partial2 = (float*)alloc((size_t)256 * 2 * 256 * 4);
    float* ss = (float*)alloc((size_t)2 * 256 * 4);
    float* g = (float*)alloc((size_t)G * 256 * 4);
    float* z1 = (float*)alloc((size_t)G * 128 * 4);
    float* z2 = (float*)alloc((size_t)G * 64 * 4);
    uint2* pairs = (uint2*)alloc((size_t)T * 8);

    // atom encoder + weight prep
    atom_enc<<<(N + 3) / 4, 256, 0, stream>>>(x, atom_emb, hb, N);
    prep_wt<<<4 * 224, 256, 0, stream>>>(bases_W, comb_W, WT);

    // fused count + bucket histogram (cnt zeroed first)
    hipMemsetAsync(cnt, 0, (size_t)N * 4, stream);
    ph_hist<<<PB, 256, 0, stream>>>(edge_index, E, T, PB, NBK, mcnt, cnt);

    // CSR row_ptr (self-loop via addone=1 in scans)
    scan_s1<<<NCHUNK, 256, 0, stream>>>(cnt, blksum, N, 1);
    scan_s2<<<1, 256, 0, stream>>>(blksum, NCHUNK, row_ptr, N);
    scan_s3<<<NCHUNK, 256, 0, stream>>>(cnt, blksum, row_ptr, woff, N, 1);

    // bucketed edge sort
    scan_s1<<<MCHUNK, 256, 0, stream>>>(mcnt, blksum, M, 0);
    scan_s2<<<1, 256, 0, stream>>>(blksum, MCHUNK, moff, M);
    scan_s3<<<MCHUNK, 256, 0, stream>>>(mcnt, blksum, moff, moff, M, 0);
    ph_scatter<<<PB, 256, 0, stream>>>(edge_index, E, T, PB, NBK, moff, pairs);
    ph_sort<<<NBK, 256, 0, stream>>>(pairs, row_ptr, moff, NBK, PB, T, srcs);

    for (int l = 0; l < 4; ++l) {
        const short* WTl = WT + (size_t)l * 224 * 256;
        const float* cb = comb_b + (size_t)l * 96;
        const float* cbias = conv_bias + (size_t)l * 256;
        const float* gam = bn_gamma + (size_t)l * 256;
        const float* bet = bn_beta + (size_t)l * 256;

        // BN-apply of previous layer fused into GEMM input path
        gemm_mfma<<<(N + 63) / 64, 256, 0, stream>>>(hb, outb, ss, l > 0 ? 1 : 0,
                                                     WTl, cb, bases, wts, N);
        agg_einsum<<<AGG_NB, 256, 0, stream>>>(bases, wts, row_ptr, srcs, cbias, outb, partial, N);
        bn_reduce<<<256, 256, 0, stream>>>(partial, AGG_NB, partial2);
        bn_finalize<<<256, 256, 0, stream>>>(partial2, 256, 256, N, gam, bet, ss);
    }

    // pool with fused layer-4 BN+residual
    pool_kernel<<<G, 256, 0, stream>>>(hb, outb, ss, batch, N, g);

    // MLP layer 1: 256 -> 128
    mlp_gemm<<<G, 128, 256 * 4, stream>>>(g, w1, z1, 256, 128);
    bn_stats<<<64, 128, 0, stream>>>(z1, G, 128, partial);
    bn_finalize<<<128, 256, 0, stream>>>(partial, 64, 128, G, g1, b1, ss);

    // MLP layer 2: 128 -> 64 (BN1 applied on input staging)
    mlp_gemm_bn<<<G, 64, 128 * 4, stream>>>(z1, ss, w2, z2, 128, 64);
    bn_stats<<<64, 64, 0, stream>>>(z2, G, 64, partial);
    bn_finalize<<<64, 256, 0, stream>>>(partial, 64, 64, G, g2, b2, ss);

    // final: 64 -> 1 (BN2 applied inline)
    final_gemm_bn<<<(G + 255) / 256, 256, 0, stream>>>(z2, ss, w3, b3, out, G);
}

// Round 17
// 540.942 us; speedup vs baseline: 1.0143x; 1.0117x over previous
//
#include <hip/hip_runtime.h>
#include <hip/hip_bf16.h>

#define HID 256
#define NGRAPH 2048

typedef __attribute__((ext_vector_type(8))) short s16x8;
typedef __attribute__((ext_vector_type(4))) float f32x4v;

__device__ inline short f2b(float f) {
    __hip_bfloat16 b = __float2bfloat16(f);
    return *reinterpret_cast<short*>(&b);
}
__device__ inline float b2f(short s) {
    return __uint_as_float(((unsigned)(unsigned short)s) << 16);
}
__device__ inline float b2f_lo(unsigned int v) {
    return __uint_as_float(v << 16);
}
__device__ inline float b2f_hi(unsigned int v) {
    return __uint_as_float(v & 0xffff0000u);
}

// ---------------- Atom encoder: 4 nodes/block, wave per node ----------------
__global__ __launch_bounds__(256) void atom_enc(const int* __restrict__ x,
                                                const float* __restrict__ emb,
                                                short* __restrict__ hb, int N) {
    int wid = threadIdx.x >> 6;
    int lane = threadIdx.x & 63;
    int n = blockIdx.x * 4 + wid;
    if (n >= N) return;
    const int offs[9] = {0, 119, 124, 136, 148, 158, 164, 170, 172};
    float s0 = 0.f, s1 = 0.f, s2 = 0.f, s3 = 0.f;
#pragma unroll
    for (int j = 0; j < 9; ++j) {
        int row = x[n * 9 + j] + offs[j];
        float4 v = *(const float4*)&emb[(size_t)row * 256 + 4 * lane];
        s0 += v.x; s1 += v.y; s2 += v.z; s3 += v.w;
    }
    short4 o;
    o.x = f2b(s0); o.y = f2b(s1); o.z = f2b(s2); o.w = f2b(s3);
    *(short4*)&hb[(size_t)n * 256 + 4 * lane] = o;
}

// ---------------- Weight prep ----------------
__global__ void prep_wt(const float* __restrict__ bases_W, const float* __restrict__ comb_W,
                        short* __restrict__ WT) {
    int l = blockIdx.x / 224;
    int n = blockIdx.x % 224;
    int k = threadIdx.x;  // 0..255
    float v = (n < 128) ? bases_W[((size_t)l * 256 + k) * 128 + n]
                        : comb_W[((size_t)l * 256 + k) * 96 + (n - 128)];
    WT[((size_t)l * 224 + n) * 256 + k] = f2b(v);
}

// hierarchical scan: S1 per-1024-chunk sums (addone: +1/elem for self-loops)
__global__ __launch_bounds__(256) void scan_s1(const int* __restrict__ cnt, int* __restrict__ blksum,
                                               int N, int addone) {
    __shared__ int red[256];
    int base = blockIdx.x * 1024;
    int s = 0;
#pragma unroll
    for (int q = 0; q < 4; ++q) {
        int i = base + threadIdx.x * 4 + q;
        s += (i < N) ? (cnt[i] + addone) : 0;
    }
    red[threadIdx.x] = s;
    __syncthreads();
    for (int off = 128; off > 0; off >>= 1) {
        if (threadIdx.x < off) red[threadIdx.x] += red[threadIdx.x + off];
        __syncthreads();
    }
    if (threadIdx.x == 0) blksum[blockIdx.x] = red[0];
}

// S2: exclusive scan of block sums (nb <= 256), writes total to row_ptr[N]
__global__ __launch_bounds__(256) void scan_s2(int* __restrict__ blksum, int nb, int* __restrict__ row_ptr, int N) {
    __shared__ int buf[256];
    int v = (threadIdx.x < nb) ? blksum[threadIdx.x] : 0;
    buf[threadIdx.x] = v;
    __syncthreads();
    for (int off = 1; off < 256; off <<= 1) {
        int t = (threadIdx.x >= off) ? buf[threadIdx.x - off] : 0;
        __syncthreads();
        buf[threadIdx.x] += t;
        __syncthreads();
    }
    if (threadIdx.x < nb) blksum[threadIdx.x] = buf[threadIdx.x] - v;  // exclusive
    if (threadIdx.x == 0) row_ptr[N] = buf[255];
}

// S3: per-chunk local scan + base; writes two copies (row_ptr, woff)
__global__ __launch_bounds__(256) void scan_s3(const int* __restrict__ cnt, const int* __restrict__ blksum,
                                               int* __restrict__ row_ptr, int* __restrict__ woff,
                                               int N, int addone) {
    __shared__ int buf[256];
    int base = blockIdx.x * 1024;
    int i0 = base + threadIdx.x * 4;
    int v[4];
    int s = 0;
#pragma unroll
    for (int q = 0; q < 4; ++q) {
        int i = i0 + q;
        v[q] = (i < N) ? (cnt[i] + addone) : 0;
        s += v[q];
    }
    buf[threadIdx.x] = s;
    __syncthreads();
    for (int off = 1; off < 256; off <<= 1) {
        int t = (threadIdx.x >= off) ? buf[threadIdx.x - off] : 0;
        __syncthreads();
        buf[threadIdx.x] += t;
        __syncthreads();
    }
    int excl = buf[threadIdx.x] - s + blksum[blockIdx.x];
#pragma unroll
    for (int q = 0; q < 4; ++q) {
        int i = i0 + q;
        if (i < N) { row_ptr[i] = excl; woff[i] = excl; }
        excl += v[q];
    }
}

// ---------------- Fused per-node count + bucketed histogram ----------------
__global__ __launch_bounds__(256) void ph_hist(const int* __restrict__ ei, int E, int T,
                                               int PB, int NBK, int* __restrict__ mcnt,
                                               int* __restrict__ cnt) {
    __shared__ int hist[256];
    hist[threadIdx.x] = 0;
    __syncthreads();
    int base = blockIdx.x * 4096;
#pragma unroll
    for (int q = 0; q < 16; ++q) {
        int i = base + q * 256 + threadIdx.x;
        if (i < T) {
            int d = (i < E) ? ei[i] : (i - E);
            atomicAdd(&hist[d >> 8], 1);
            if (i < E) atomicAdd(&cnt[d], 1);
        }
    }
    __syncthreads();
    if (threadIdx.x < NBK) mcnt[threadIdx.x * PB + blockIdx.x] = hist[threadIdx.x];
}

__global__ __launch_bounds__(256) void ph_scatter(const int* __restrict__ ei, int E, int T,
                                                  int PB, int NBK, const int* __restrict__ moff,
                                                  uint2* __restrict__ pairs) {
    __shared__ int off[256];
    if (threadIdx.x < NBK) off[threadIdx.x] = moff[threadIdx.x * PB + blockIdx.x];
    __syncthreads();
    int base = blockIdx.x * 4096;
#pragma unroll
    for (int q = 0; q < 16; ++q) {
        int i = base + q * 256 + threadIdx.x;
        if (i < T) {
            int d, s;
            if (i < E) { d = ei[i]; s = ei[E + i]; }
            else       { d = i - E; s = i - E; }
            int pos = atomicAdd(&off[d >> 8], 1);
            pairs[pos] = make_uint2((unsigned)d, (unsigned)s);
        }
    }
}

__global__ __launch_bounds__(256) void ph_sort(const uint2* __restrict__ pairs,
                                               const int* __restrict__ row_ptr,
                                               const int* __restrict__ moff,
                                               int NBK, int PB, int T,
                                               int* __restrict__ srcs) {
    __shared__ int wcnt[256];
    wcnt[threadIdx.x] = 0;
    __syncthreads();
    int bin = blockIdx.x;
    int p0 = moff[bin * PB];
    int p1 = (bin + 1 < NBK) ? moff[(bin + 1) * PB] : T;
    for (int i = p0 + threadIdx.x; i < p1; i += 256) {
        uint2 u = pairs[i];
        int d = (int)u.x;
        int rank = atomicAdd(&wcnt[d & 255], 1);
        srcs[row_ptr[d] + rank] = (int)u.y;
    }
}

// ---------------- MFMA GEMM, fused BN-apply+residual, all-bf16 h/outb/wts ----------------
__global__ __launch_bounds__(256) void gemm_mfma(short* hb,
                                                 const short* __restrict__ outb,
                                                 const float* __restrict__ ss,
                                                 int do_bn,
                                                 const short* __restrict__ WT,
                                                 const float* __restrict__ cb,
                                                 short* __restrict__ bases,
                                                 short* __restrict__ wts, int N) {
    __shared__ short bs[2][32 * 256];  // 2 x 16KB
    int tid = threadIdx.x;
    int wid = tid >> 6;
    int lane = tid & 63;
    int m0 = blockIdx.x * 64 + wid * 16;
    int row_orig = m0 + (lane & 15);
    bool owner = (row_orig < N);
    int row_a = owner ? row_orig : (N - 1);
    int kgrp = (lane >> 4) * 8;  // 0,8,16,24

    s16x8 a[8];
    if (do_bn) {
#pragma unroll
        for (int i = 0; i < 8; ++i) {
            int cbase = i * 32 + kgrp;
            size_t base = (size_t)row_a * 256 + cbase;
            s16x8 hv = *(const s16x8*)&hb[base];
            s16x8 ov = *(const s16x8*)&outb[base];
            s16x8 t;
#pragma unroll
            for (int k = 0; k < 8; ++k) {
                float hf = b2f(hv[k]);
                float of = b2f(ov[k]);
                float sc = ss[cbase + k];
                float sh = ss[256 + cbase + k];
                hf += fmaxf(of * sc + sh, 0.f);
                t[k] = f2b(hf);
            }
            if (owner) *(s16x8*)&hb[base] = t;
            a[i] = t;
        }
    } else {
#pragma unroll
        for (int i = 0; i < 8; ++i) {
            size_t base = (size_t)row_a * 256 + i * 32 + kgrp;
            a[i] = *(const s16x8*)&hb[base];
        }
    }

    int st_col = tid >> 3;
    int st_kk = (tid & 7) * 32;
    int st_sw = (st_col & 7) << 4;
    int st_base = st_col * 512 + st_kk * 2;

    auto stage = [&](int buf, int t) {
        const s16x8* src = (const s16x8*)&WT[(size_t)(t * 32 + st_col) * 256 + st_kk];
        char* dst = (char*)bs[buf];
#pragma unroll
        for (int q = 0; q < 4; ++q)
            *(s16x8*)(dst + ((st_base + q * 16) ^ st_sw)) = src[q];
    };

    stage(0, 0);

    int col = lane & 15;
    int rd_base = col * 512 + (lane >> 4) * 16;
    int rd_sw = (col & 7) << 4;
    int rbase = m0 + (lane >> 4) * 4;

    for (int t = 0; t < 7; ++t) {
        __syncthreads();
        if (t + 1 < 7) stage((t + 1) & 1, t + 1);

        const char* base = (const char*)bs[t & 1];
        f32x4v c0 = {0.f, 0.f, 0.f, 0.f};
        f32x4v c1 = {0.f, 0.f, 0.f, 0.f};
#pragma unroll
        for (int i = 0; i < 8; ++i) {
            s16x8 b0 = *(const s16x8*)(base + ((rd_base + i * 64) ^ rd_sw));
            s16x8 b1 = *(const s16x8*)(base + ((rd_base + 8192 + i * 64) ^ rd_sw));
            c0 = __builtin_amdgcn_mfma_f32_16x16x32_bf16(a[i], b0, c0, 0, 0, 0);
            c1 = __builtin_amdgcn_mfma_f32_16x16x32_bf16(a[i], b1, c1, 0, 0, 0);
        }

        int cc0 = t * 32 + col;
        int cc1 = cc0 + 16;
        float cb0 = (cc0 >= 128) ? cb[cc0 - 128] : 0.f;
        float cb1 = (cc1 >= 128) ? cb[cc1 - 128] : 0.f;
#pragma unroll
        for (int r = 0; r < 4; ++r) {
            int row = rbase + r;
            if (row >= N) continue;
            float v0 = c0[r], v1 = c1[r];
            if (cc0 < 128) bases[(size_t)row * 128 + cc0] = f2b(v0);
            else wts[(size_t)row * 96 + (cc0 - 128)] = f2b(v0 + cb0);
            if (cc1 < 128) bases[(size_t)row * 128 + cc1] = f2b(v1);
            else wts[(size_t)row * 96 + (cc1 - 128)] = f2b(v1 + cb1);
        }
    }
}

// ---------------- Aggregation v7 (proven): 1 node/wave, 8B gathers, half-wave pairs ----------------
__global__ __launch_bounds__(256) void agg_einsum(const short* __restrict__ bases,
                                                  const short* __restrict__ wts,
                                                  const int* __restrict__ row_ptr,
                                                  const int* __restrict__ srcs,
                                                  const float* __restrict__ cbias,
                                                  short* __restrict__ outp,
                                                  float* __restrict__ partial, int N) {
    __shared__ float agg_lds[4][3][128];
    __shared__ float wts_lds[4][96];
    __shared__ float red[4][256];
    int wid = threadIdx.x >> 6;
    int lane = threadIdx.x & 63;
    int n = blockIdx.x * 4 + wid;
    bool valid = (n < N);

    int r0 = 0, r1 = 0;
    if (valid) {
        r0 = row_ptr[n];
        r1 = row_ptr[n + 1];
        wts_lds[wid][lane] = b2f(wts[(size_t)n * 96 + lane]);
        if (lane < 32) wts_lds[wid][64 + lane] = b2f(wts[(size_t)n * 96 + 64 + lane]);
    }

    int g = lane & 31;     // channel group: bf16 channels 4g..4g+3
    int half = lane >> 5;  // which edge of each pair
    const short* bp = bases + 4 * g;
    const float NI = -3.402823466e+38f;
    float sA0 = 0.f, sA1 = 0.f, sA2 = 0.f, sA3 = 0.f;
    float sB0 = 0.f, sB1 = 0.f, sB2 = 0.f, sB3 = 0.f;
    float mA0 = NI, mA1 = NI, mA2 = NI, mA3 = NI;
    float mB0 = NI, mB1 = NI, mB2 = NI, mB3 = NI;

#define GACC8(S, s0_, s1_, s2_, s3_, m0_, m1_, m2_, m3_)                     \
    {                                                                        \
        uint2 v = *(const uint2*)&bp[(size_t)(S) * 128];                     \
        float f0 = b2f_lo(v.x), f1 = b2f_hi(v.x);                            \
        float f2 = b2f_lo(v.y), f3 = b2f_hi(v.y);                            \
        s0_ += f0; s1_ += f1; s2_ += f2; s3_ += f3;                          \
        m0_ = fmaxf(m0_, f0); m1_ = fmaxf(m1_, f1);                          \
        m2_ = fmaxf(m2_, f2); m3_ = fmaxf(m3_, f3);                          \
    }

    int r = r0;
    while (r < r1) {
        int chunk = r1 - r;
        if (chunk > 64) chunk = 64;
        int sidx = (lane < chunk) ? srcs[r + lane] : 0;
        int npair = chunk >> 1;
        int jp = 0;
        for (; jp + 4 <= npair; jp += 4) {
            int e0 = (jp + 0) * 2 + half, e1 = (jp + 1) * 2 + half;
            int e2 = (jp + 2) * 2 + half, e3 = (jp + 3) * 2 + half;
            int s0 = __shfl(sidx, e0), s1 = __shfl(sidx, e1);
            int s2 = __shfl(sidx, e2), s3 = __shfl(sidx, e3);
            GACC8(s0, sA0, sA1, sA2, sA3, mA0, mA1, mA2, mA3);
            GACC8(s1, sB0, sB1, sB2, sB3, mB0, mB1, mB2, mB3);
            GACC8(s2, sA0, sA1, sA2, sA3, mA0, mA1, mA2, mA3);
            GACC8(s3, sB0, sB1, sB2, sB3, mB0, mB1, mB2, mB3);
        }
        for (; jp < npair; ++jp) {
            int e0 = jp * 2 + half;
            int s0 = __shfl(sidx, e0);
            GACC8(s0, sA0, sA1, sA2, sA3, mA0, mA1, mA2, mA3);
        }
        if (chunk & 1) {
            int s0 = __shfl(sidx, chunk - 1);
            if (half == 0) {
                GACC8(s0, sB0, sB1, sB2, sB3, mB0, mB1, mB2, mB3);
            }
        }
        r += chunk;
    }
#undef GACC8

    float accs[4] = {0.f, 0.f, 0.f, 0.f};
    if (valid) {
        float s0 = sA0 + sB0, s1 = sA1 + sB1, s2 = sA2 + sB2, s3 = sA3 + sB3;
        float m0 = fmaxf(mA0, mB0), m1 = fmaxf(mA1, mB1);
        float m2 = fmaxf(mA2, mB2), m3 = fmaxf(mA3, mB3);
        s0 += __shfl_xor(s0, 32); s1 += __shfl_xor(s1, 32);
        s2 += __shfl_xor(s2, 32); s3 += __shfl_xor(s3, 32);
        m0 = fmaxf(m0, __shfl_xor(m0, 32)); m1 = fmaxf(m1, __shfl_xor(m1, 32));
        m2 = fmaxf(m2, __shfl_xor(m2, 32)); m3 = fmaxf(m3, __shfl_xor(m3, 32));

        float inv = 1.0f / (float)(r1 - r0);
        if (half == 0) {
            float4 sv = make_float4(s0, s1, s2, s3);
            float4 mv = make_float4(s0 * inv, s1 * inv, s2 * inv, s3 * inv);
            float4 xv = make_float4(m0, m1, m2, m3);
            *(float4*)&agg_lds[wid][0][4 * g] = sv;
            *(float4*)&agg_lds[wid][1][4 * g] = mv;
            *(float4*)&agg_lds[wid][2][4 * g] = xv;
        }

        asm volatile("s_waitcnt lgkmcnt(0)" ::: "memory");

#pragma unroll
        for (int j = 0; j < 4; ++j) {
            int o = lane + 64 * j;
            int hh = o >> 5;
            int d = o & 31;
            float acc = cbias[o];
#pragma unroll
            for (int k = 0; k < 12; ++k)
                acc = fmaf(wts_lds[wid][hh * 12 + k], agg_lds[wid][k >> 2][(k & 3) * 32 + d], acc);
            outp[(size_t)n * 256 + o] = f2b(acc);
            accs[j] = acc;
        }
    }
    // block-level BN partial (deterministic, fp32 pre-rounding)
#pragma unroll
    for (int j = 0; j < 4; ++j) red[wid][lane + 64 * j] = accs[j];
    __syncthreads();
    int c = threadIdx.x;
    float s = (red[0][c] + red[1][c]) + (red[2][c] + red[3][c]);
    float s2 = (red[0][c] * red[0][c] + red[1][c] * red[1][c]) +
               (red[2][c] * red[2][c] + red[3][c] * red[3][c]);
    partial[((size_t)blockIdx.x * 2 + 0) * 256 + c] = s;
    partial[((size_t)blockIdx.x * 2 + 1) * 256 + c] = s2;
}

// ---------------- BN coalesced tree reduce: NB partials -> 256 partials ----------------
__global__ __launch_bounds__(256) void bn_reduce(const float* __restrict__ partial, int NB,
                                                 float* __restrict__ partial2) {
    int t = threadIdx.x;
    int chunk = (NB + 255) / 256;
    int rbeg = blockIdx.x * chunk;
    int rend = min(NB, rbeg + chunk);
    float s = 0.f, s2 = 0.f;
    for (int r = rbeg; r < rend; ++r) {
        s += partial[((size_t)r * 2 + 0) * 256 + t];
        s2 += partial[((size_t)r * 2 + 1) * 256 + t];
    }
    partial2[((size_t)blockIdx.x * 2 + 0) * 256 + t] = s;
    partial2[((size_t)blockIdx.x * 2 + 1) * 256 + t] = s2;
}

// ---------------- BN stats (generic, small inputs / MLP) ----------------
__global__ void bn_stats(const float* __restrict__ v, int N, int C, float* __restrict__ partial) {
    int c = threadIdx.x;  // blockDim == C
    float s = 0.f, s2 = 0.f;
    for (int r = blockIdx.x; r < N; r += gridDim.x) {
        float t = v[r * C + c];
        s += t; s2 += t * t;
    }
    partial[(blockIdx.x * 2 + 0) * C + c] = s;
    partial[(blockIdx.x * 2 + 1) * C + c] = s2;
}

// parallel finalize: one block per channel
__global__ __launch_bounds__(256) void bn_finalize(const float* __restrict__ partial, int NB, int C, int N,
                                                   const float* __restrict__ gamma, const float* __restrict__ beta,
                                                   float* __restrict__ ss) {
    int c = blockIdx.x;
    float s = 0.f, s2 = 0.f;
    for (int b = threadIdx.x; b < NB; b += 256) {
        s += partial[((size_t)b * 2 + 0) * C + c];
        s2 += partial[((size_t)b * 2 + 1) * C + c];
    }
#pragma unroll
    for (int off = 32; off > 0; off >>= 1) {
        s += __shfl_down(s, off);
        s2 += __shfl_down(s2, off);
    }
    __shared__ float wsum[4][2];
    int wid = threadIdx.x >> 6;
    int lane = threadIdx.x & 63;
    if (lane == 0) { wsum[wid][0] = s; wsum[wid][1] = s2; }
    __syncthreads();
    if (threadIdx.x == 0) {
        s = (wsum[0][0] + wsum[1][0]) + (wsum[2][0] + wsum[3][0]);
        s2 = (wsum[0][1] + wsum[1][1]) + (wsum[2][1] + wsum[3][1]);
        float invN = 1.0f / (float)N;
        float mu = s * invN;
        float var = fmaxf(s2 * invN - mu * mu, 0.f);
        float sc = gamma[c] * rsqrtf(var + 1e-5f);
        ss[c] = sc;
        ss[C + c] = beta[c] - mu * sc;
    }
}

// ---------------- Pool with fused final BN+residual ----------------
__device__ int lower_bound_dev(const int* a, int n, int v) {
    int lo = 0, hi = n;
    while (lo < hi) {
        int mid = (lo + hi) >> 1;
        if (a[mid] < v) lo = mid + 1; else hi = mid;
    }
    return lo;
}

__global__ __launch_bounds__(256) void pool_kernel(const short* __restrict__ hb,
                                                   const short* __restrict__ outb,
                                                   const float* __restrict__ ss,
                                                   const int* __restrict__ batch, int N,
                                                   float* __restrict__ g) {
    __shared__ int sh[2];
    if (threadIdx.x == 0) {
        sh[0] = lower_bound_dev(batch, N, (int)blockIdx.x);
        sh[1] = lower_bound_dev(batch, N, (int)blockIdx.x + 1);
    }
    __syncthreads();
    int s0 = sh[0], s1 = sh[1];
    int c = threadIdx.x;
    float sc = ss[c], shf = ss[256 + c];
    float s = 0.f;
    for (int r = s0; r < s1; ++r) {
        size_t idx = (size_t)r * 256 + c;
        float hf = b2f(hb[idx]) + fmaxf(b2f(outb[idx]) * sc + shf, 0.f);
        s += hf;
    }
    float cnt = (float)(s1 - s0);
    g[blockIdx.x * 256 + c] = s / fmaxf(cnt, 1.0f);
}

// ---------------- MLP ----------------
__global__ void mlp_gemm(const float* __restrict__ in, const float* __restrict__ W,
                         float* __restrict__ outp, int K, int C) {
    extern __shared__ float srow[];
    int r = blockIdx.x;
    for (int k = threadIdx.x; k < K; k += blockDim.x) srow[k] = in[r * K + k];
    __syncthreads();
    int c = threadIdx.x;
    float acc = 0.f;
    for (int k = 0; k < K; ++k) acc = fmaf(srow[k], W[k * C + c], acc);
    outp[r * C + c] = acc;
}

// same, but applies relu(in*sc+sh) with ssb[0:K]=scale, ssb[K:2K]=shift when staging
__global__ void mlp_gemm_bn(const float* __restrict__ in, const float* __restrict__ ssb,
                            const float* __restrict__ W,
                            float* __restrict__ outp, int K, int C) {
    extern __shared__ float srow[];
    int r = blockIdx.x;
    for (int k = threadIdx.x; k < K; k += blockDim.x)
        srow[k] = fmaxf(in[r * K + k] * ssb[k] + ssb[K + k], 0.f);
    __syncthreads();
    int c = threadIdx.x;
    float acc = 0.f;
    for (int k = 0; k < K; ++k) acc = fmaf(srow[k], W[k * C + c], acc);
    outp[r * C + c] = acc;
}

__global__ void final_gemm_bn(const float* __restrict__ z2, const float* __restrict__ ssb,
                              const float* __restrict__ w3,
                              const float* __restrict__ b3, float* __restrict__ outp, int G) {
    int g = blockIdx.x * blockDim.x + threadIdx.x;
    if (g >= G) return;
    float acc = b3[0];
    for (int k = 0; k < 64; ++k) {
        float z = fmaxf(z2[g * 64 + k] * ssb[k] + ssb[64 + k], 0.f);
        acc = fmaf(z, w3[k], acc);
    }
    outp[g] = acc;
}

extern "C" void kernel_launch(void* const* d_in, const int* in_sizes, int n_in,
                              void* d_out, int out_size, void* d_ws, size_t ws_size,
                              hipStream_t stream) {
    const float* atom_emb = (const float*)d_in[0];
    const float* bases_W = (const float*)d_in[1];
    const float* comb_W = (const float*)d_in[2];
    const float* comb_b = (const float*)d_in[3];
    const float* conv_bias = (const float*)d_in[4];
    const float* bn_gamma = (const float*)d_in[5];
    const float* bn_beta = (const float*)d_in[6];
    const float* w1 = (const float*)d_in[7];
    const float* g1 = (const float*)d_in[8];
    const float* b1 = (const float*)d_in[9];
    const float* w2 = (const float*)d_in[10];
    const float* g2 = (const float*)d_in[11];
    const float* b2 = (const float*)d_in[12];
    const float* w3 = (const float*)d_in[13];
    const float* b3 = (const float*)d_in[14];
    const int* x = (const int*)d_in[15];
    const int* edge_index = (const int*)d_in[16];
    const int* batch = (const int*)d_in[17];
    float* out = (float*)d_out;

    const int N = in_sizes[15] / 9;
    const int E = in_sizes[16] / 2;
    const int G = NGRAPH;
    const int T = E + N;
    const int NCHUNK = (N + 1023) / 1024;
    const int PB = (T + 4095) / 4096;        // phase blocks
    const int NBK = (N + 255) >> 8;          // dst buckets (<=256)
    const int M = NBK * PB;                  // histogram matrix size
    const int MCHUNK = (M + 1023) / 1024;
    const int AGG_NB = (N + 3) / 4;          // agg grid / BN partial count

    // workspace carve
    char* p = (char*)d_ws;
    auto alloc = [&](size_t bytes) -> void* {
        void* r = (void*)p;
        p += (bytes + 255) & ~(size_t)255;
        return r;
    };
    short* hb = (short*)alloc((size_t)N * 256 * 2);
    short* outb = (short*)alloc((size_t)N * 256 * 2);
    short* bases = (short*)alloc((size_t)N * 128 * 2);
    short* wts = (short*)alloc((size_t)N * 96 * 2);
    short* WT = (short*)alloc((size_t)4 * 224 * 256 * 2);
    int* row_ptr = (int*)alloc((size_t)(N + 1) * 4);
    int* cnt = (int*)alloc((size_t)N * 4);
    int* woff = (int*)alloc((size_t)N * 4);
    int* blksum = (int*)alloc((size_t)256 * 4);
    int* mcnt = (int*)alloc((size_t)(M + 1) * 4);
    int* moff = (int*)alloc((size_t)(M + 1) * 4);
    int* srcs = (int*)alloc((size_t)T * 4);
    float* partial = (float*)alloc((size_t)AGG_NB * 2 * 256 * 4);
    float* partial2 = (float*)alloc((size_t)256 * 2 * 256 * 4);
    float* ss = (float*)alloc((size_t)2 * 256 * 4);
    float* g = (float*)alloc((size_t)G * 256 * 4);
    float* z1 = (float*)alloc((size_t)G * 128 * 4);
    float* z2 = (float*)alloc((size_t)G * 64 * 4);
    uint2* pairs = (uint2*)alloc((size_t)T * 8);

    // atom encoder + weight prep
    atom_enc<<<(N + 3) / 4, 256, 0, stream>>>(x, atom_emb, hb, N);
    prep_wt<<<4 * 224, 256, 0, stream>>>(bases_W, comb_W, WT);

    // fused count + bucket histogram (cnt zeroed first)
    hipMemsetAsync(cnt, 0, (size_t)N * 4, stream);
    ph_hist<<<PB, 256, 0, stream>>>(edge_index, E, T, PB, NBK, mcnt, cnt);

    // CSR row_ptr (self-loop via addone=1 in scans)
    scan_s1<<<NCHUNK, 256, 0, stream>>>(cnt, blksum, N, 1);
    scan_s2<<<1, 256, 0, stream>>>(blksum, NCHUNK, row_ptr, N);
    scan_s3<<<NCHUNK, 256, 0, stream>>>(cnt, blksum, row_ptr, woff, N, 1);

    // bucketed edge sort
    scan_s1<<<MCHUNK, 256, 0, stream>>>(mcnt, blksum, M, 0);
    scan_s2<<<1, 256, 0, stream>>>(blksum, MCHUNK, moff, M);
    scan_s3<<<MCHUNK, 256, 0, stream>>>(mcnt, blksum, moff, moff, M, 0);
    ph_scatter<<<PB, 256, 0, stream>>>(edge_index, E, T, PB, NBK, moff, pairs);
    ph_sort<<<NBK, 256, 0, stream>>>(pairs, row_ptr, moff, NBK, PB, T, srcs);

    for (int l = 0; l < 4; ++l) {
        const short* WTl = WT + (size_t)l * 224 * 256;
        const float* cb = comb_b + (size_t)l * 96;
        const float* cbias = conv_bias + (size_t)l * 256;
        const float* gam = bn_gamma + (size_t)l * 256;
        const float* bet = bn_beta + (size_t)l * 256;

        // BN-apply of previous layer fused into GEMM input path
        gemm_mfma<<<(N + 63) / 64, 256, 0, stream>>>(hb, outb, ss, l > 0 ? 1 : 0,
                                                     WTl, cb, bases, wts, N);
        agg_einsum<<<AGG_NB, 256, 0, stream>>>(bases, wts, row_ptr, srcs, cbias, outb, partial, N);
        bn_reduce<<<256, 256, 0, stream>>>(partial, AGG_NB, partial2);
        bn_finalize<<<256, 256, 0, stream>>>(partial2, 256, 256, N, gam, bet, ss);
    }

    // pool with fused layer-4 BN+residual
    pool_kernel<<<G, 256, 0, stream>>>(hb, outb, ss, batch, N, g);

    // MLP layer 1: 256 -> 128
    mlp_gemm<<<G, 128, 256 * 4, stream>>>(g, w1, z1, 256, 128);
    bn_stats<<<64, 128, 0, stream>>>(z1, G, 128, partial);
    bn_finalize<<<128, 256, 0, stream>>>(partial, 64, 128, G, g1, b1, ss);

    // MLP layer 2: 128 -> 64 (BN1 applied on input staging)
    mlp_gemm_bn<<<G, 64, 128 * 4, stream>>>(z1, ss, w2, z2, 128, 64);
    bn_stats<<<64, 64, 0, stream>>>(z2, G, 64, partial);
    bn_finalize<<<64, 256, 0, stream>>>(partial, 64, 64, G, g2, b2, ss);

    // final: 64 -> 1 (BN2 applied inline)
    final_gemm_bn<<<(G + 255) / 256, 256, 0, stream>>>(z2, ss, w3, b3, out, G);
}